// Round 1
// baseline (317.962 us; speedup 1.0000x reference)
//
#include <hip/hip_runtime.h>

typedef __attribute__((ext_vector_type(8))) short short8;
typedef __attribute__((ext_vector_type(4))) float f32x4;
typedef __attribute__((ext_vector_type(4))) unsigned short us4;

#define SCL2 0.18033688011112042f   /* 64^-0.5 * log2(e) */

__device__ __forceinline__ unsigned short f2bf(float f) {
  unsigned u = __builtin_bit_cast(unsigned, f);
  u += 0x7FFFu + ((u >> 16) & 1u);          // RNE round to bf16
  return (unsigned short)(u >> 16);
}

__global__ __launch_bounds__(256, 2)
void lattn(const float* __restrict__ Qg, const float* __restrict__ Kg,
           const float* __restrict__ Vg, float* __restrict__ Og) {
  constexpr int S = 8192, H = 16, D = 64, RS = H * D;  // RS floats between s steps
  __shared__ __align__(16) unsigned char smem[49152];
  unsigned char* Klds = smem;            // [64 k][64 d] bf16, chunk-XOR swizzled (8 KB)
  unsigned char* Vlds = smem + 8192;     // [64 d][64 k] bf16 (V transposed), swizzled (8 KB)

  const int tid = threadIdx.x;
  const int l = tid & 63, w = tid >> 6;
  const int g = l >> 4, l15 = l & 15;
  unsigned char* Plds = smem + 16384 + w * 8192;  // per-wave [64 q][64 k] bf16, swizzled

  const int bid = blockIdx.x;
  const int n = bid & 31, h = (bid >> 5) & 15, b = bid >> 9;

  const float* Qp = Qg + (size_t)b * S * RS + h * D;
  const float* Kp = Kg + (size_t)b * S * RS + h * D;
  const float* Vp = Vg + (size_t)b * S * RS + h * D;
  float*       Op = Og + (size_t)b * S * RS + h * D;

  const int wq0 = w * 64;            // wave's first q row within the block
  const int qg0 = n * 256 + wq0;     // global q row

  // ---- Q fragments (held in registers): q = l15+16*nr, d = g*8+32*ks..+7
  short8 qf[2][4];
#pragma unroll
  for (int nr = 0; nr < 4; ++nr) {
    const float* qrow = Qp + (size_t)(qg0 + 16 * nr + l15) * RS;
#pragma unroll
    for (int ks = 0; ks < 2; ++ks) {
      float4 a = *(const float4*)(qrow + g * 8 + 32 * ks);
      float4 c = *(const float4*)(qrow + g * 8 + 32 * ks + 4);
      short8 v;
      v[0] = (short)f2bf(a.x); v[1] = (short)f2bf(a.y);
      v[2] = (short)f2bf(a.z); v[3] = (short)f2bf(a.w);
      v[4] = (short)f2bf(c.x); v[5] = (short)f2bf(c.y);
      v[6] = (short)f2bf(c.z); v[7] = (short)f2bf(c.w);
      qf[ks][nr] = v;
    }
  }

  f32x4 acc[4][4];                   // O accumulator [q-block][d-block]
#pragma unroll
  for (int i = 0; i < 4; ++i)
#pragma unroll
    for (int j = 0; j < 4; ++j) acc[i][j] = f32x4{0.f, 0.f, 0.f, 0.f};
  float m_run[4] = {-1e20f, -1e20f, -1e20f, -1e20f};   // floor avoids exp2(0)=1 on all-masked tiles
  float l_run[4] = {0.f, 0.f, 0.f, 0.f};

  const int kvb = (n - 1) * 256;     // window start; negative only when n==0 (tiles skipped)
  const int t0 = (n == 0) ? 4 : 0;

  for (int t = t0; t < 8; ++t) {
    __syncthreads();                 // protect K/V LDS from previous iteration's readers
    // ---- stage K tile (row-major, swizzled): 2 chunks of 8 floats per thread
#pragma unroll
    for (int cc = 0; cc < 2; ++cc) {
      int cid = tid + 256 * cc;
      int r = cid >> 3, ch = cid & 7;
      const float* src = Kp + (size_t)(kvb + t * 64 + r) * RS + ch * 8;
      float4 a = *(const float4*)(src);
      float4 c = *(const float4*)(src + 4);
      short8 v;
      v[0] = (short)f2bf(a.x); v[1] = (short)f2bf(a.y);
      v[2] = (short)f2bf(a.z); v[3] = (short)f2bf(a.w);
      v[4] = (short)f2bf(c.x); v[5] = (short)f2bf(c.y);
      v[6] = (short)f2bf(c.z); v[7] = (short)f2bf(c.w);
      *(short8*)(Klds + r * 128 + ((ch ^ (r & 7)) << 4)) = v;
    }
    // ---- stage V transposed ([d][k], swizzled): 8 column floats per chunk
#pragma unroll
    for (int cc = 0; cc < 2; ++cc) {
      int cid = tid + 256 * cc;
      int d = cid & 63, kc = cid >> 6;   // kc in 0..7 across the two cc
      const float* src = Vp + (size_t)(kvb + t * 64 + kc * 8) * RS + d;
      short8 v;
#pragma unroll
      for (int i = 0; i < 8; ++i) v[i] = (short)f2bf(src[(size_t)i * RS]);
      *(short8*)(Vlds + d * 128 + ((kc ^ (d & 7)) << 4)) = v;
    }
    __syncthreads();

    // ---- S^T = K · Q^T  (rows = k, cols = q): per-wave 64x64
    f32x4 s[4][4];
#pragma unroll
    for (int i = 0; i < 4; ++i)
#pragma unroll
      for (int j = 0; j < 4; ++j) s[i][j] = f32x4{0.f, 0.f, 0.f, 0.f};
#pragma unroll
    for (int ks = 0; ks < 2; ++ks) {
      short8 kf[4];
#pragma unroll
      for (int mr = 0; mr < 4; ++mr) {
        int r = mr * 16 + l15;
        int c = g + 4 * ks;
        kf[mr] = *(const short8*)(Klds + r * 128 + (((c ^ (r & 7)) & 7) << 4));
      }
#pragma unroll
      for (int mr = 0; mr < 4; ++mr)
#pragma unroll
        for (int nr = 0; nr < 4; ++nr)
          s[mr][nr] = __builtin_amdgcn_mfma_f32_16x16x32_bf16(kf[mr], qf[ks][nr],
                                                              s[mr][nr], 0, 0, 0);
    }

    // ---- mask + scale into log2 domain (in place)
    // element (mr,nr,reg): koff = t*64 + mr*16 + g*4 + reg (window offset 0..511)
    //                      q    = wq0 + 16*nr + l15        (block-local query)
    float rmax[4];
#pragma unroll
    for (int nr = 0; nr < 4; ++nr) {
      int q = wq0 + 16 * nr + l15;
      float mx = -1e30f;
#pragma unroll
      for (int mr = 0; mr < 4; ++mr)
#pragma unroll
        for (int reg = 0; reg < 4; ++reg) {
          int koff = t * 64 + mr * 16 + g * 4 + reg;
          bool valid = (koff > q) && (koff <= q + 256);
          float sv = valid ? s[mr][nr][reg] * SCL2 : -1e30f;
          s[mr][nr][reg] = sv;
          mx = fmaxf(mx, sv);
        }
      rmax[nr] = mx;
    }
#pragma unroll
    for (int nr = 0; nr < 4; ++nr) {
      float mx = rmax[nr];
      mx = fmaxf(mx, __shfl_xor(mx, 16));
      mx = fmaxf(mx, __shfl_xor(mx, 32));
      rmax[nr] = mx;
    }
    float corr[4];
#pragma unroll
    for (int nr = 0; nr < 4; ++nr) {
      float mnew = fmaxf(m_run[nr], rmax[nr]);
      corr[nr] = exp2f(m_run[nr] - mnew);
      m_run[nr] = mnew;
      float sum = 0.f;
#pragma unroll
      for (int mr = 0; mr < 4; ++mr)
#pragma unroll
        for (int reg = 0; reg < 4; ++reg) {
          float p = exp2f(s[mr][nr][reg] - mnew);
          s[mr][nr][reg] = p;
          sum += p;
        }
      sum += __shfl_xor(sum, 16);
      sum += __shfl_xor(sum, 32);
      l_run[nr] = l_run[nr] * corr[nr] + sum;
    }
    // ---- rescale O (corr is q-indexed by l15; O rows are q-indexed by g*4+reg)
#pragma unroll
    for (int mr = 0; mr < 4; ++mr)
#pragma unroll
      for (int reg = 0; reg < 4; ++reg) {
        float c = __shfl(corr[mr], g * 4 + reg, 16);
#pragma unroll
        for (int nr = 0; nr < 4; ++nr) acc[mr][nr][reg] *= c;
      }
    // ---- write P to per-wave LDS [q][k] bf16 (4 consecutive k per 8B write)
#pragma unroll
    for (int nr = 0; nr < 4; ++nr)
#pragma unroll
      for (int mr = 0; mr < 4; ++mr) {
        int q = 16 * nr + l15;                 // wave-local q row
        int cb = 2 * mr + (g >> 1);            // 16B chunk of k bytes 32*mr+8*g
        int off = q * 128 + ((cb ^ (q & 7)) << 4) + 8 * (g & 1);
        us4 pk;
        pk[0] = f2bf(s[mr][nr][0]); pk[1] = f2bf(s[mr][nr][1]);
        pk[2] = f2bf(s[mr][nr][2]); pk[3] = f2bf(s[mr][nr][3]);
        *(us4*)(Plds + off) = pk;
      }
    asm volatile("s_waitcnt lgkmcnt(0)" ::: "memory");  // cross-lane LDS RAW within wave

    // ---- O += P · V   (A = P rows q, B = V^T rows d, both contiguous b128)
#pragma unroll
    for (int ks = 0; ks < 2; ++ks) {
      short8 pf[4], vf[4];
#pragma unroll
      for (int mr = 0; mr < 4; ++mr) {
        int q = 16 * mr + l15;
        int c = g + 4 * ks;
        pf[mr] = *(const short8*)(Plds + q * 128 + (((c ^ (q & 7)) & 7) << 4));
      }
#pragma unroll
      for (int nr = 0; nr < 4; ++nr) {
        int d = 16 * nr + l15;
        int c = g + 4 * ks;
        vf[nr] = *(const short8*)(Vlds + d * 128 + (((c ^ (d & 7)) & 7) << 4));
      }
#pragma unroll
      for (int mr = 0; mr < 4; ++mr)
#pragma unroll
        for (int nr = 0; nr < 4; ++nr)
          acc[mr][nr] = __builtin_amdgcn_mfma_f32_16x16x32_bf16(pf[mr], vf[nr],
                                                                acc[mr][nr], 0, 0, 0);
    }
  }

  // ---- finalize: divide by l, store fp32
  float linv[4];
#pragma unroll
  for (int nr = 0; nr < 4; ++nr) linv[nr] = 1.0f / l_run[nr];
#pragma unroll
  for (int mr = 0; mr < 4; ++mr)
#pragma unroll
    for (int reg = 0; reg < 4; ++reg) {
      float li = __shfl(linv[mr], g * 4 + reg, 16);
      int qrow = qg0 + 16 * mr + g * 4 + reg;
      float* orow = Op + (size_t)qrow * RS;
#pragma unroll
      for (int nr = 0; nr < 4; ++nr)
        orow[16 * nr + l15] = acc[mr][nr][reg] * li;
    }
}

extern "C" void kernel_launch(void* const* d_in, const int* in_sizes, int n_in,
                              void* d_out, int out_size, void* d_ws, size_t ws_size,
                              hipStream_t stream) {
  (void)in_sizes; (void)n_in; (void)d_ws; (void)ws_size; (void)out_size;
  const float* q = (const float*)d_in[0];
  const float* k = (const float*)d_in[1];
  const float* v = (const float*)d_in[2];
  float* o = (float*)d_out;
  dim3 grid(2 * 16 * 32);   // B * H * n_blocks = 1024 workgroups
  dim3 block(256);
  lattn<<<grid, block, 0, stream>>>(q, k, v, o);
}